// Round 1
// baseline (143.613 us; speedup 1.0000x reference)
//
#include <hip/hip_runtime.h>
#include <cmath>

#define BLOCK 256

// acc layout: per batch b, 4 floats: [pos_count, stc_sum, str_sum, pad]
__global__ void __launch_bounds__(BLOCK) ainno_main(
    const float* __restrict__ ss,       // (B, A, 6)
    const float* __restrict__ anchors,  // (A, 4) xywh
    const float* __restrict__ gt,       // (B, K, 4) xywh
    float* __restrict__ acc,
    int A, int K)
{
    extern __shared__ char smem_raw[];
    float4* gbox = (float4*)smem_raw;      // xyxy per gt
    float*  gar  = (float*)(gbox + K);     // area per gt
    float*  red  = gar + K;                // (BLOCK/64)*3 reduction slots

    const int b   = blockIdx.y;
    const int tid = threadIdx.x;

    // Stage GT boxes (xyxy + area) into LDS, replicating reference arithmetic:
    // x2 = x + w; area = (x2 - x) * (y2 - y)
    const float4* gtb = (const float4*)(gt + (size_t)b * K * 4);
    for (int k = tid; k < K; k += BLOCK) {
        float4 g = gtb[k];
        float x2 = g.x + g.z, y2 = g.y + g.w;
        gbox[k] = make_float4(g.x, g.y, x2, y2);
        gar[k]  = (x2 - g.x) * (y2 - g.y);
    }
    __syncthreads();

    const int a = blockIdx.x * BLOCK + tid;
    float posf = 0.f, stc = 0.f, strt = 0.f;
    if (a < A) {
        float4 an = ((const float4*)anchors)[a];
        float ax = an.x, ay = an.y;
        float ax2 = an.x + an.z, ay2 = an.y + an.w;
        float aarea = (ax2 - ax) * (ay2 - ay);

        // argmax of inter/den via cross-multiplication (den > 0 always here):
        // avoids K divides per anchor; one divide at the end reproduces the
        // reference's iou value bit-for-bit for the winning k.
        float bi = -1.f, bd = 1.f;   // best inter / best den (bi=-1 => k=0 always wins first)
        int bk = 0;
        for (int k = 0; k < K; ++k) {
            float4 g = gbox[k];
            float w = fminf(ax2, g.z) - fmaxf(ax, g.x);
            float h = fminf(ay2, g.w) - fmaxf(ay, g.y);
            w = fmaxf(w, 0.f); h = fmaxf(h, 0.f);
            float inter = w * h;
            float den = aarea + gar[k] - inter;
            if (inter * bd > bi * den) { bi = inter; bd = den; bk = k; }
        }
        float score = bi / bd;             // == ref max IoU (same operands)
        bool pos = score >= 0.5f;
        bool neg = score < 0.4f;

        const float* sp = ss + ((size_t)b * A + a) * 6;
        if (pos | neg) {
            float x = sp[4];
            float e = expf(-x);
            float p = 1.f / (1.f + e);
            if (pos) {
                posf = 1.f;
                float ce  = log1pf(e);          // softplus(-x) = -log_sigmoid(x)
                float omp = 1.f - p;
                stc = 0.25f * ce * omp * omp;

                // elementwise IoU: pred box vs matched gt box
                float px = sp[0], py = sp[1];
                float px2 = px + sp[2], py2 = py + sp[3];
                float4 g = gbox[bk];
                float ew = fminf(px2, g.z) - fmaxf(px, g.x);
                float eh = fminf(py2, g.w) - fmaxf(py, g.y);
                ew = fmaxf(ew, 0.f); eh = fmaxf(eh, 0.f);
                float einter = ew * eh;
                float pa = (px2 - px) * (py2 - py);
                float eiou = einter / (pa + gar[bk] - einter);
                strt = -logf(eiou + 0.01f);
            } else {
                float ce = log1pf(expf(x));     // softplus(x) = -log_sigmoid(-x)
                stc = 0.75f * ce * p * p;
            }
        }
    }

    // block reduction: wave64 shuffle, then LDS across waves, then 3 atomics
    float v0 = posf, v1 = stc, v2 = strt;
    for (int off = 32; off > 0; off >>= 1) {
        v0 += __shfl_down(v0, off, 64);
        v1 += __shfl_down(v1, off, 64);
        v2 += __shfl_down(v2, off, 64);
    }
    const int wave = tid >> 6, lane = tid & 63;
    if (lane == 0) {
        red[wave * 3 + 0] = v0;
        red[wave * 3 + 1] = v1;
        red[wave * 3 + 2] = v2;
    }
    __syncthreads();
    if (tid == 0) {
        float s0 = 0.f, s1 = 0.f, s2 = 0.f;
        const int NW = BLOCK / 64;
        for (int w = 0; w < NW; ++w) {
            s0 += red[w * 3 + 0];
            s1 += red[w * 3 + 1];
            s2 += red[w * 3 + 2];
        }
        atomicAdd(&acc[b * 4 + 0], s0);
        atomicAdd(&acc[b * 4 + 1], s1);
        atomicAdd(&acc[b * 4 + 2], s2);
    }
}

__global__ void ainno_finalize(const float* __restrict__ acc,
                               float* __restrict__ out, int B)
{
    if (threadIdx.x == 0 && blockIdx.x == 0) {
        float tot = 0.f;
        for (int b = 0; b < B; ++b) {
            float pc  = acc[b * 4 + 0];
            float stc = acc[b * 4 + 1];
            float st  = acc[b * 4 + 2];
            float safe = pc > 0.f ? pc : 1.f;
            tot += stc / safe;
            if (pc > 0.f) tot += st / safe;
        }
        out[0] = tot / (float)B;
    }
}

extern "C" void kernel_launch(void* const* d_in, const int* in_sizes, int n_in,
                              void* d_out, int out_size, void* d_ws, size_t ws_size,
                              hipStream_t stream) {
    const float* ss      = (const float*)d_in[0];
    const float* anchors = (const float*)d_in[1];
    const float* gt      = (const float*)d_in[2];
    float* out = (float*)d_out;
    float* acc = (float*)d_ws;

    const int A = in_sizes[1] / 4;
    const int B = in_sizes[0] / (A * 6);
    const int K = in_sizes[2] / (B * 4);

    // zero the per-batch accumulators (d_ws is poisoned 0xAA before each call)
    hipMemsetAsync(acc, 0, (size_t)B * 4 * sizeof(float), stream);

    dim3 grid((A + BLOCK - 1) / BLOCK, B);
    size_t shmem = (size_t)K * sizeof(float4)         // gbox
                 + (size_t)K * sizeof(float)          // gar
                 + (BLOCK / 64) * 3 * sizeof(float);  // red
    ainno_main<<<grid, BLOCK, shmem, stream>>>(ss, anchors, gt, acc, A, K);
    ainno_finalize<<<1, 64, 0, stream>>>(acc, out, B);
}

// Round 2
// 117.017 us; speedup vs baseline: 1.2273x; 1.2273x over previous
//
#include <hip/hip_runtime.h>
#include <cmath>

#define BLOCK 256
#define APT 2   // anchors per thread

__device__ __forceinline__ float rlane_f(float v, int k) {
    return __builtin_bit_cast(float, __builtin_amdgcn_readlane(__builtin_bit_cast(int, v), k));
}

// acc layout: per batch b, 4 floats [pos_count, stc_sum, str_sum, pad];
// acc[4*B] (as int) is the block-completion counter. All zeroed by memsetAsync.
__global__ void __launch_bounds__(BLOCK) ainno_main(
    const float* __restrict__ ss,       // (B, A, 6)
    const float* __restrict__ anchors,  // (A, 4) xywh
    const float* __restrict__ gt,       // (B, K, 4) xywh
    float* __restrict__ acc,
    float* __restrict__ out,
    int A, int K, int B)
{
    __shared__ float red[(BLOCK / 64) * 3];
    const int b    = blockIdx.y;
    const int tid  = threadIdx.x;
    const int lane = tid & 63;

    // Distributed GT boxes: lane k of every wave holds box k (K <= 64).
    // Same arithmetic as reference: x2 = x + w, area = (x2-x)*(y2-y).
    float gx1 = 0.f, gy1 = 0.f, gx2 = 0.f, gy2 = 0.f, garr = 0.f;
    if (lane < K) {
        float4 g = ((const float4*)(gt + (size_t)b * K * 4))[lane];
        gx1 = g.x; gy1 = g.y; gx2 = g.x + g.z; gy2 = g.y + g.w;
        garr = (gx2 - gx1) * (gy2 - gy1);
    }

    const int base = blockIdx.x * (BLOCK * APT) + tid;

    float ax[APT], ay[APT], axx[APT], ayy[APT], aar[APT];
    float bi[APT], bd[APT];
    int   bk[APT];
    #pragma unroll
    for (int i = 0; i < APT; ++i) {
        int a  = base + i * BLOCK;
        int ac = a < A ? a : A - 1;      // clamp; contribution guarded later
        float4 an = ((const float4*)anchors)[ac];
        ax[i]  = an.x;         ay[i]  = an.y;
        axx[i] = an.x + an.z;  ayy[i] = an.y + an.w;
        aar[i] = (axx[i] - ax[i]) * (ayy[i] - ay[i]);
        bi[i] = -1.f; bd[i] = 1.f; bk[i] = 0;
    }

    // Hot loop: pure VALU. 5 readlanes broadcast box k, then per-anchor
    // cross-multiplied argmax (one divide total, after the loop, with the
    // same operands the reference divides -> bit-identical winning IoU).
    #pragma unroll 4
    for (int k = 0; k < K; ++k) {
        float sx1 = rlane_f(gx1, k);
        float sy1 = rlane_f(gy1, k);
        float sx2 = rlane_f(gx2, k);
        float sy2 = rlane_f(gy2, k);
        float sar = rlane_f(garr, k);
        #pragma unroll
        for (int i = 0; i < APT; ++i) {
            float w = fminf(axx[i], sx2) - fmaxf(ax[i], sx1);
            float h = fminf(ayy[i], sy2) - fmaxf(ay[i], sy1);
            w = fmaxf(w, 0.f); h = fmaxf(h, 0.f);
            float inter = w * h;
            float den = aar[i] + sar - inter;
            bool better = inter * bd[i] > bi[i] * den;  // strict > keeps first max (ref argmax)
            bi[i] = better ? inter : bi[i];
            bd[i] = better ? den   : bd[i];
            bk[i] = better ? k     : bk[i];
        }
    }

    float posf = 0.f, stcs = 0.f, strs = 0.f;
    #pragma unroll
    for (int i = 0; i < APT; ++i) {
        int a = base + i * BLOCK;
        // Gather winning box via wave shuffle (bk divergent -> ds_bpermute).
        // Hoisted out of divergent branches: inactive-lane reads are undefined.
        float bx1 = __shfl(gx1,  bk[i], 64);
        float by1 = __shfl(gy1,  bk[i], 64);
        float bx2 = __shfl(gx2,  bk[i], 64);
        float by2 = __shfl(gy2,  bk[i], 64);
        float bar = __shfl(garr, bk[i], 64);

        float score = bi[i] / bd[i];     // == ref max IoU (same operands)
        bool inb = a < A;
        bool pos = inb && (score >= 0.5f);
        bool neg = inb && (score < 0.4f);
        if (pos | neg) {
            const float* sp = ss + ((size_t)b * A + a) * 6;
            float x = sp[4];
            float e = expf(-x);
            float p = 1.f / (1.f + e);
            if (pos) {
                posf += 1.f;
                float ce  = log1pf(e);           // softplus(-x) = -log_sigmoid(x)
                float omp = 1.f - p;
                stcs += 0.25f * ce * omp * omp;

                float px  = sp[0], py = sp[1];
                float pxx = px + sp[2], pyy = py + sp[3];
                float ew = fminf(pxx, bx2) - fmaxf(px, bx1);
                float eh = fminf(pyy, by2) - fmaxf(py, by1);
                ew = fmaxf(ew, 0.f); eh = fmaxf(eh, 0.f);
                float einter = ew * eh;
                float pa = (pxx - px) * (pyy - py);
                float eiou = einter / (pa + bar - einter);
                strs += -logf(eiou + 0.01f);
            } else {
                float ce = log1pf(expf(x));      // softplus(x) = -log_sigmoid(-x)
                stcs += 0.75f * ce * p * p;
            }
        }
    }

    // wave64 shuffle reduction -> LDS across waves -> 3 atomics per block
    float v0 = posf, v1 = stcs, v2 = strs;
    for (int off = 32; off > 0; off >>= 1) {
        v0 += __shfl_down(v0, off, 64);
        v1 += __shfl_down(v1, off, 64);
        v2 += __shfl_down(v2, off, 64);
    }
    const int wave = tid >> 6;
    if (lane == 0) {
        red[wave * 3 + 0] = v0;
        red[wave * 3 + 1] = v1;
        red[wave * 3 + 2] = v2;
    }
    __syncthreads();
    if (tid == 0) {
        float s0 = 0.f, s1 = 0.f, s2 = 0.f;
        for (int w = 0; w < BLOCK / 64; ++w) {
            s0 += red[w * 3 + 0];
            s1 += red[w * 3 + 1];
            s2 += red[w * 3 + 2];
        }
        atomicAdd(&acc[b * 4 + 0], s0);
        atomicAdd(&acc[b * 4 + 1], s1);
        atomicAdd(&acc[b * 4 + 2], s2);
        __threadfence();
        int total = gridDim.x * gridDim.y;
        int old = atomicAdd((int*)(acc + 4 * B), 1);
        if (old == total - 1) {
            // last block finalizes; read partials with device-scope atomics
            // (plain loads could hit a stale per-XCD L2 line)
            float tot = 0.f;
            for (int bb = 0; bb < B; ++bb) {
                float pc = atomicAdd(&acc[bb * 4 + 0], 0.f);
                float st = atomicAdd(&acc[bb * 4 + 1], 0.f);
                float sr = atomicAdd(&acc[bb * 4 + 2], 0.f);
                float safe = pc > 0.f ? pc : 1.f;
                tot += st / safe;
                if (pc > 0.f) tot += sr / safe;
            }
            out[0] = tot / (float)B;
        }
    }
}

extern "C" void kernel_launch(void* const* d_in, const int* in_sizes, int n_in,
                              void* d_out, int out_size, void* d_ws, size_t ws_size,
                              hipStream_t stream) {
    const float* ss      = (const float*)d_in[0];
    const float* anchors = (const float*)d_in[1];
    const float* gt      = (const float*)d_in[2];
    float* out = (float*)d_out;
    float* acc = (float*)d_ws;

    const int A = in_sizes[1] / 4;
    const int B = in_sizes[0] / (A * 6);
    const int K = in_sizes[2] / (B * 4);

    // zero accumulators + completion counter (d_ws is poisoned each call)
    hipMemsetAsync(acc, 0, ((size_t)B * 4 + 1) * sizeof(float), stream);

    dim3 grid((A + BLOCK * APT - 1) / (BLOCK * APT), B);
    ainno_main<<<grid, BLOCK, 0, stream>>>(ss, anchors, gt, acc, out, A, K, B);
}